// Round 6
// baseline (221.456 us; speedup 1.0000x reference)
//
#include <hip/hip_runtime.h>
#include <hip/hip_bf16.h>
#include <math.h>

// Problem: B=4, T=2048, C=1024, H=16, D=64
// out = proj( attention( x @ W_attn + b_attn ) ) + b_proj

typedef __bf16 bf16x8 __attribute__((ext_vector_type(8)));
typedef float f32x4 __attribute__((ext_vector_type(4)));

__device__ __forceinline__ f32x4 mfma16(bf16x8 a, bf16x8 b, f32x4 c) {
    return __builtin_amdgcn_mfma_f32_16x16x32_bf16(a, b, c, 0, 0, 0);
}

#define GLOBAL_AS __attribute__((address_space(1)))
#define LDS_AS __attribute__((address_space(3)))

// async 16B/lane global->LDS (dest is wave-uniform base + lane*16)
__device__ __forceinline__ void async_copy16(const __hip_bfloat16* g, __hip_bfloat16* l) {
    __builtin_amdgcn_global_load_lds((const GLOBAL_AS uint32_t*)g, (LDS_AS uint32_t*)l, 16, 0, 0);
}

// q is pre-scaled by 0.125*log2(e) so softmax exps are pure exp2
#define QSCL 0.18033688011112042f

// ---- cast x (fp32) -> bf16, 8 elems/thread ----
__global__ __launch_bounds__(256) void cast_x_kernel(const float* __restrict__ in,
                                                     __hip_bfloat16* __restrict__ out, int n) {
    int i = (blockIdx.x * 256 + threadIdx.x) * 8;
    if (i >= n) return;
    union { __hip_bfloat16 h[8]; uint4 v; } tmp;
#pragma unroll
    for (int j = 0; j < 8; ++j) tmp.h[j] = __float2bfloat16(in[i + j]);
    *reinterpret_cast<uint4*>(out + i) = tmp.v;
}

// ---- transpose+cast: in[R][Cc] fp32 -> out[Cc][R] bf16 ----
__global__ __launch_bounds__(256) void transpose_cast_kernel(const float* __restrict__ in,
                                                             __hip_bfloat16* __restrict__ out,
                                                             int R, int Cc) {
    __shared__ float tile[32][33];
    int c0 = blockIdx.x * 32, r0 = blockIdx.y * 32;
    int tx = threadIdx.x & 31, ty = threadIdx.x >> 5;  // ty 0..7
#pragma unroll
    for (int i = 0; i < 4; ++i) {
        int r = r0 + ty + i * 8;
        tile[ty + i * 8][tx] = in[(size_t)r * Cc + c0 + tx];
    }
    __syncthreads();
#pragma unroll
    for (int i = 0; i < 4; ++i) {
        int c = c0 + ty + i * 8;
        out[(size_t)c * R + r0 + tx] = __float2bfloat16(tile[tx][ty + i * 8]);
    }
}

// ================= m97-style 128x128 GEMM core =================
#define GEMM128_BODY(A_, Bt_, K_)                                                       \
    __shared__ __hip_bfloat16 As[128 * 32];                                             \
    __shared__ __hip_bfloat16 Bs[128 * 32];                                             \
    const int tid = threadIdx.x;                                                        \
    const int w = tid >> 6;                                                             \
    const int lr = tid & 15, lh = (tid & 63) >> 4;                                      \
    const int wr = w >> 1, wc = w & 1;                                                  \
    f32x4 zero = {0.f, 0.f, 0.f, 0.f};                                                  \
    f32x4 acc[4][4];                                                                    \
    _Pragma("unroll") for (int i = 0; i < 4; ++i)                                       \
        _Pragma("unroll") for (int j = 0; j < 4; ++j) acc[i][j] = zero;                 \
    for (int k0 = 0; k0 < (K_); k0 += 32) {                                             \
        _Pragma("unroll") for (int i = 0; i < 2; ++i) {                                 \
            int t = i * 256 + tid;                                                      \
            async_copy16((A_) + (size_t)(m0 + (t >> 2)) * (K_) + k0 + (t & 3) * 8,      \
                         As + (size_t)(i * 256 + w * 64) * 8);                          \
            async_copy16((Bt_) + (size_t)(n0 + (t >> 2)) * (K_) + k0 + (t & 3) * 8,     \
                         Bs + (size_t)(i * 256 + w * 64) * 8);                          \
        }                                                                               \
        __syncthreads();                                                                \
        bf16x8 af[4], bf[4];                                                            \
        _Pragma("unroll") for (int mf = 0; mf < 4; ++mf)                                \
            af[mf] = *reinterpret_cast<const bf16x8*>(                                  \
                &As[(wr * 64 + mf * 16 + lr) * 32 + lh * 8]);                           \
        _Pragma("unroll") for (int nf = 0; nf < 4; ++nf)                                \
            bf[nf] = *reinterpret_cast<const bf16x8*>(                                  \
                &Bs[(wc * 64 + nf * 16 + lr) * 32 + lh * 8]);                           \
        _Pragma("unroll") for (int mf = 0; mf < 4; ++mf)                                \
            _Pragma("unroll") for (int nf = 0; nf < 4; ++nf)                            \
                acc[mf][nf] = mfma16(af[mf], bf[nf], acc[mf][nf]);                      \
        __syncthreads();                                                                \
    }

// ---- QKV GEMM ----
__global__ __launch_bounds__(256) void gemm_qkv_kernel(
    const __hip_bfloat16* __restrict__ A, const __hip_bfloat16* __restrict__ Bt,
    const float* __restrict__ bias,
    __hip_bfloat16* __restrict__ qd, __hip_bfloat16* __restrict__ kd,
    __hip_bfloat16* __restrict__ vtd) {
    const int K = 1024;
    const int m0 = blockIdx.x * 128;
    const int n0 = blockIdx.y * 128;
    GEMM128_BODY(A, Bt, K)

    const int region = n0 >> 10;  // 0:q 1:k 2:v (block-uniform)
#pragma unroll
    for (int mf = 0; mf < 4; ++mf) {
#pragma unroll
        for (int nf = 0; nf < 4; ++nf) {
            int n = n0 + wc * 64 + nf * 16 + lr;
            float bv = bias[n];
            int mbase = m0 + wr * 64 + mf * 16 + 4 * lh;
            int bb = mbase >> 11;
            int t = mbase & 2047;
            int c = n & 1023, hh = c >> 6, dd = c & 63;
            if (region == 2) {
                union { __hip_bfloat16 h[4]; uint2 v; } pk;
#pragma unroll
                for (int r = 0; r < 4; ++r) pk.h[r] = __float2bfloat16(acc[mf][nf][r] + bv);
                *reinterpret_cast<uint2*>(
                    &vtd[(((size_t)bb * 16 + hh) * 64 + dd) * 2048 + t]) = pk.v;
            } else if (region == 0) {
#pragma unroll
                for (int r = 0; r < 4; ++r)
                    qd[(((size_t)bb * 16 + hh) * 2048 + t + r) * 64 + dd] =
                        __float2bfloat16((acc[mf][nf][r] + bv) * QSCL);
            } else {
#pragma unroll
                for (int r = 0; r < 4; ++r)
                    kd[(((size_t)bb * 16 + hh) * 2048 + t + r) * 64 + dd] =
                        __float2bfloat16(acc[mf][nf][r] + bv);
            }
        }
    }
}

// ---- proj GEMM ----
__global__ __launch_bounds__(256) void gemm_proj_kernel(
    const __hip_bfloat16* __restrict__ A, const __hip_bfloat16* __restrict__ Bt,
    const float* __restrict__ bias, float* __restrict__ out) {
    const int K = 1024, N = 1024;
    const int m0 = blockIdx.x * 128;
    const int n0 = blockIdx.y * 128;
    GEMM128_BODY(A, Bt, K)

#pragma unroll
    for (int nf = 0; nf < 4; ++nf) {
        int n = n0 + wc * 64 + nf * 16 + lr;
        float bv = bias[n];
#pragma unroll
        for (int mf = 0; mf < 4; ++mf) {
            int mbase = m0 + wr * 64 + mf * 16 + 4 * lh;
#pragma unroll
            for (int r = 0; r < 4; ++r)
                out[(size_t)(mbase + r) * N + n] = acc[mf][nf][r] + bv;
        }
    }
}

// ---- causal flash attention v5 ----
// 1024 blocks (1D, XCD-swizzled). Block owns q-tiles x and 31-x (64 rows each,
// 4 waves x 16 rows) and sweeps kv tiles t=0..31-x ONCE, sharing the staged
// K/V tile (and the LDS fragment reads) between both q-tiles.
// Double-buffered staging with counted vmcnt(4) + raw barriers (T3/T4).
__global__ __launch_bounds__(256) void attn_kernel(
    const __hip_bfloat16* __restrict__ q, const __hip_bfloat16* __restrict__ k,
    const __hip_bfloat16* __restrict__ vt, __hip_bfloat16* __restrict__ y) {
    const int T = 2048, D = 64, C = 1024;
    const float THR = 8.0f;

    // XCD swizzle: each XCD gets 128 consecutive works = 8 whole heads
    int wid = ((int)blockIdx.x & 7) * 128 + ((int)blockIdx.x >> 3);
    int bh = wid >> 4;
    int x = wid & 15;  // pair id
    int b = bh >> 4, h = bh & 15;
    int tid = threadIdx.x;
    int w = tid >> 6, l = tid & 63;
    int lr = l & 15, lh = l >> 4;

    __shared__ __hip_bfloat16 Ks[2][64 * 64];  // [buf][kv][d], xor-swizzled rows
    __shared__ __hip_bfloat16 Vs[2][64 * 64];  // [buf][d][kv], xor-swizzled rows
    __shared__ __hip_bfloat16 P[4][16][72];

    const __hip_bfloat16* kbh = k + (size_t)bh * T * D;
    const __hip_bfloat16* vbh = vt + (size_t)bh * D * T;

    const int qtl = x, qth = 31 - x;
    const int q0l = qtl * 64 + w * 16, q0h = qth * 64 + w * 16;
    const int nt = qth + 1;

    // Q frags for both tiles
    bf16x8 qaL[2], qaH[2];
#pragma unroll
    for (int dd = 0; dd < 2; ++dd) {
        qaL[dd] = *reinterpret_cast<const bf16x8*>(
            q + ((size_t)bh * T + q0l + lr) * D + 32 * dd + 8 * lh);
        qaH[dd] = *reinterpret_cast<const bf16x8*>(
            q + ((size_t)bh * T + q0h + lr) * D + 32 * dd + 8 * lh);
    }

    f32x4 zero = {0.f, 0.f, 0.f, 0.f};
    f32x4 oL[4] = {zero, zero, zero, zero}, oH[4] = {zero, zero, zero, zero};
    float mL[4], lpL[4], mH[4], lpH[4];
#pragma unroll
    for (int r = 0; r < 4; ++r) {
        mL[r] = -INFINITY; lpL[r] = 0.f;
        mH[r] = -INFINITY; lpH[r] = 0.f;
    }

    auto stage = [&](int bufi, int t) {
        int kv0 = t * 64;
#pragma unroll
        for (int j = 0; j < 2; ++j) {
            int slot = j * 256 + tid;
            int row = slot >> 3;
            int colb = ((slot & 7) * 16) ^ ((row & 7) << 4);
            async_copy16(kbh + (size_t)(kv0 + row) * 64 + (colb >> 1),
                         &Ks[bufi][(size_t)(j * 256 + w * 64) * 8]);
            async_copy16(vbh + (size_t)row * T + kv0 + (colb >> 1),
                         &Vs[bufi][(size_t)(j * 256 + w * 64) * 8]);
        }
    };

    stage(0, 0);

    for (int t = 0; t < nt; ++t) {
        int cur = t & 1;
        if (t + 1 < nt) {
            stage(cur ^ 1, t + 1);
            asm volatile("s_waitcnt vmcnt(4)" ::: "memory");
        } else {
            asm volatile("s_waitcnt vmcnt(0)" ::: "memory");
        }
        __builtin_amdgcn_s_barrier();
        __builtin_amdgcn_sched_barrier(0);

        const int kv0 = t * 64;
        const bool doL = (t <= qtl);
        const char* KsB = reinterpret_cast<const char*>(&Ks[cur][0]);
        const char* VsB = reinterpret_cast<const char*>(&Vs[cur][0]);

        // K frags from LDS (swizzled) — shared by both q-tiles
        bf16x8 kb[4][2];
#pragma unroll
        for (int ct = 0; ct < 4; ++ct)
#pragma unroll
            for (int dd = 0; dd < 2; ++dd) {
                int row = 16 * ct + lr;
                int colb = (dd * 64 + lh * 16) ^ ((lr & 7) << 4);
                kb[ct][dd] = *reinterpret_cast<const bf16x8*>(KsB + row * 128 + colb);
            }

        f32x4 sH[4], sL[4];
#pragma unroll
        for (int ct = 0; ct < 4; ++ct) {
            f32x4 a = zero;
            a = mfma16(qaH[0], kb[ct][0], a);
            a = mfma16(qaH[1], kb[ct][1], a);
            sH[ct] = a;
        }
        if (doL) {
#pragma unroll
            for (int ct = 0; ct < 4; ++ct) {
                f32x4 a = zero;
                a = mfma16(qaL[0], kb[ct][0], a);
                a = mfma16(qaL[1], kb[ct][1], a);
                sL[ct] = a;
            }
        }

        // V frags (shared by both PV steps); issue early so latency hides
        bf16x8 vb[4][2];
#pragma unroll
        for (int dt = 0; dt < 4; ++dt)
#pragma unroll
            for (int kk = 0; kk < 2; ++kk) {
                int row = 16 * dt + lr;
                int colb = (kk * 64 + lh * 16) ^ ((lr & 7) << 4);
                vb[dt][kk] = *reinterpret_cast<const bf16x8*>(VsB + row * 128 + colb);
            }

        // diagonal masks
        if (t == qth) {
#pragma unroll
            for (int ct = 0; ct < 4; ++ct)
#pragma unroll
                for (int r = 0; r < 4; ++r) {
                    int qq = q0h + 4 * lh + r;
                    int kc = kv0 + 16 * ct + lr;
                    if (kc > qq) sH[ct][r] = -INFINITY;
                }
        }
        if (doL && t == qtl) {
#pragma unroll
            for (int ct = 0; ct < 4; ++ct)
#pragma unroll
                for (int r = 0; r < 4; ++r) {
                    int qq = q0l + 4 * lh + r;
                    int kc = kv0 + 16 * ct + lr;
                    if (kc > qq) sL[ct][r] = -INFINITY;
                }
        }

        // online softmax + PV for one q-tile (s destroyed)
        auto softmax_pv = [&](f32x4 (&s)[4], f32x4 (&o)[4], float (&m)[4], float (&lp)[4]) {
            float mx[4];
#pragma unroll
            for (int r = 0; r < 4; ++r)
                mx[r] = fmaxf(fmaxf(s[0][r], s[1][r]), fmaxf(s[2][r], s[3][r]));
#pragma unroll
            for (int d = 1; d < 16; d <<= 1)
#pragma unroll
                for (int r = 0; r < 4; ++r) mx[r] = fmaxf(mx[r], __shfl_xor(mx[r], d, 16));

            bool small = (mx[0] - m[0] <= THR) && (mx[1] - m[1] <= THR) &&
                         (mx[2] - m[2] <= THR) && (mx[3] - m[3] <= THR);
            if (!__all(small)) {
#pragma unroll
                for (int r = 0; r < 4; ++r) {
                    float mnew = fmaxf(m[r], mx[r]);
                    float al = __builtin_amdgcn_exp2f(m[r] - mnew);
                    m[r] = mnew;
                    lp[r] *= al;
#pragma unroll
                    for (int dt = 0; dt < 4; ++dt) o[dt][r] *= al;
                }
            }
#pragma unroll
            for (int ct = 0; ct < 4; ++ct)
#pragma unroll
                for (int r = 0; r < 4; ++r)
                    s[ct][r] = __builtin_amdgcn_exp2f(s[ct][r] - m[r]);
#pragma unroll
            for (int r = 0; r < 4; ++r)
                lp[r] += (s[0][r] + s[1][r]) + (s[2][r] + s[3][r]);

#pragma unroll
            for (int ct = 0; ct < 4; ++ct)
#pragma unroll
                for (int r = 0; r < 4; ++r)
                    P[w][4 * lh + r][16 * ct + lr] = __float2bfloat16(s[ct][r]);

            bf16x8 pa0 = *reinterpret_cast<const bf16x8*>(&P[w][lr][8 * lh]);
            bf16x8 pa1 = *reinterpret_cast<const bf16x8*>(&P[w][lr][32 + 8 * lh]);
#pragma unroll
            for (int dt = 0; dt < 4; ++dt) {
                o[dt] = mfma16(pa0, vb[dt][0], o[dt]);
                o[dt] = mfma16(pa1, vb[dt][1], o[dt]);
            }
        };

        softmax_pv(sH, oH, mH, lpH);
        if (doL) softmax_pv(sL, oL, mL, lpL);

        __builtin_amdgcn_sched_barrier(0);
        __builtin_amdgcn_s_barrier();  // close compute before next stage overwrites buf
    }

    // epilogue: reduce row sums and write both q-tiles
    auto epilogue = [&](f32x4 (&o)[4], float (&lp)[4], int q0) {
#pragma unroll
        for (int d = 1; d < 16; d <<= 1)
#pragma unroll
            for (int r = 0; r < 4; ++r) lp[r] += __shfl_xor(lp[r], d, 16);
        float inv[4];
#pragma unroll
        for (int r = 0; r < 4; ++r) inv[r] = 1.0f / lp[r];
#pragma unroll
        for (int dt = 0; dt < 4; ++dt)
#pragma unroll
            for (int r = 0; r < 4; ++r) {
                int qq = q0 + 4 * lh + r;
                y[((size_t)b * T + qq) * C + h * 64 + dt * 16 + lr] =
                    __float2bfloat16(o[dt][r] * inv[r]);
            }
    };
    epilogue(oH, lpH, q0h);
    epilogue(oL, lpL, q0l);
}

extern "C" void kernel_launch(void* const* d_in, const int* in_sizes, int n_in,
                              void* d_out, int out_size, void* d_ws, size_t ws_size,
                              hipStream_t stream) {
    const float* x      = (const float*)d_in[0];
    const float* W_attn = (const float*)d_in[1];
    const float* b_attn = (const float*)d_in[2];
    const float* W_proj = (const float*)d_in[3];
    const float* b_proj = (const float*)d_in[4];
    float* out = (float*)d_out;

    __hip_bfloat16* wsb = reinterpret_cast<__hip_bfloat16*>(d_ws);
    __hip_bfloat16* xb  = wsb;                              // 8192*1024
    __hip_bfloat16* WaT = xb + (size_t)8192 * 1024;         // 3072*1024
    __hip_bfloat16* WpT = WaT + (size_t)3072 * 1024;        // 1024*1024
    __hip_bfloat16* qd  = WpT + (size_t)1024 * 1024;        // 64*2048*64
    __hip_bfloat16* kd  = qd + (size_t)64 * 2048 * 64;
    __hip_bfloat16* vtd = kd + (size_t)64 * 2048 * 64;
    __hip_bfloat16* ya  = vtd + (size_t)64 * 2048 * 64;     // 8192*1024

    cast_x_kernel<<<4096, 256, 0, stream>>>(x, xb, 8192 * 1024);
    transpose_cast_kernel<<<dim3(96, 32), 256, 0, stream>>>(W_attn, WaT, 1024, 3072);
    transpose_cast_kernel<<<dim3(32, 32), 256, 0, stream>>>(W_proj, WpT, 1024, 1024);
    gemm_qkv_kernel<<<dim3(64, 24), 256, 0, stream>>>(xb, WaT, b_attn, qd, kd, vtd);
    attn_kernel<<<1024, 256, 0, stream>>>(qd, kd, vtd, ya);
    gemm_proj_kernel<<<dim3(64, 8), 256, 0, stream>>>(ya, WpT, b_proj, out);
}

// Round 7
// 220.551 us; speedup vs baseline: 1.0041x; 1.0041x over previous
//
#include <hip/hip_runtime.h>
#include <hip/hip_bf16.h>
#include <math.h>

// Problem: B=4, T=2048, C=1024, H=16, D=64
// out = proj( attention( x @ W_attn + b_attn ) ) + b_proj

typedef __bf16 bf16x8 __attribute__((ext_vector_type(8)));
typedef float f32x4 __attribute__((ext_vector_type(4)));

__device__ __forceinline__ f32x4 mfma16(bf16x8 a, bf16x8 b, f32x4 c) {
    return __builtin_amdgcn_mfma_f32_16x16x32_bf16(a, b, c, 0, 0, 0);
}

#define GLOBAL_AS __attribute__((address_space(1)))
#define LDS_AS __attribute__((address_space(3)))

// async 16B/lane global->LDS (dest is wave-uniform base + lane*16)
__device__ __forceinline__ void async_copy16(const __hip_bfloat16* g, __hip_bfloat16* l) {
    __builtin_amdgcn_global_load_lds((const GLOBAL_AS uint32_t*)g, (LDS_AS uint32_t*)l, 16, 0, 0);
}

// q is pre-scaled by 0.125*log2(e) so softmax exps are pure exp2
#define QSCL 0.18033688011112042f

// ---- cast x (fp32) -> bf16, 8 elems/thread ----
__global__ __launch_bounds__(256) void cast_x_kernel(const float* __restrict__ in,
                                                     __hip_bfloat16* __restrict__ out, int n) {
    int i = (blockIdx.x * 256 + threadIdx.x) * 8;
    if (i >= n) return;
    union { __hip_bfloat16 h[8]; uint4 v; } tmp;
#pragma unroll
    for (int j = 0; j < 8; ++j) tmp.h[j] = __float2bfloat16(in[i + j]);
    *reinterpret_cast<uint4*>(out + i) = tmp.v;
}

// ---- transpose+cast: in[R][Cc] fp32 -> out[Cc][R] bf16 ----
__global__ __launch_bounds__(256) void transpose_cast_kernel(const float* __restrict__ in,
                                                             __hip_bfloat16* __restrict__ out,
                                                             int R, int Cc) {
    __shared__ float tile[32][33];
    int c0 = blockIdx.x * 32, r0 = blockIdx.y * 32;
    int tx = threadIdx.x & 31, ty = threadIdx.x >> 5;  // ty 0..7
#pragma unroll
    for (int i = 0; i < 4; ++i) {
        int r = r0 + ty + i * 8;
        tile[ty + i * 8][tx] = in[(size_t)r * Cc + c0 + tx];
    }
    __syncthreads();
#pragma unroll
    for (int i = 0; i < 4; ++i) {
        int c = c0 + ty + i * 8;
        out[(size_t)c * R + r0 + tx] = __float2bfloat16(tile[tx][ty + i * 8]);
    }
}

// ================= m97-style 128x128 GEMM core =================
#define GEMM128_BODY(A_, Bt_, K_)                                                       \
    __shared__ __hip_bfloat16 As[128 * 32];                                             \
    __shared__ __hip_bfloat16 Bs[128 * 32];                                             \
    const int tid = threadIdx.x;                                                        \
    const int w = tid >> 6;                                                             \
    const int lr = tid & 15, lh = (tid & 63) >> 4;                                      \
    const int wr = w >> 1, wc = w & 1;                                                  \
    f32x4 zero = {0.f, 0.f, 0.f, 0.f};                                                  \
    f32x4 acc[4][4];                                                                    \
    _Pragma("unroll") for (int i = 0; i < 4; ++i)                                       \
        _Pragma("unroll") for (int j = 0; j < 4; ++j) acc[i][j] = zero;                 \
    for (int k0 = 0; k0 < (K_); k0 += 32) {                                             \
        _Pragma("unroll") for (int i = 0; i < 2; ++i) {                                 \
            int t = i * 256 + tid;                                                      \
            async_copy16((A_) + (size_t)(m0 + (t >> 2)) * (K_) + k0 + (t & 3) * 8,      \
                         As + (size_t)(i * 256 + w * 64) * 8);                          \
            async_copy16((Bt_) + (size_t)(n0 + (t >> 2)) * (K_) + k0 + (t & 3) * 8,     \
                         Bs + (size_t)(i * 256 + w * 64) * 8);                          \
        }                                                                               \
        __syncthreads();                                                                \
        bf16x8 af[4], bf[4];                                                            \
        _Pragma("unroll") for (int mf = 0; mf < 4; ++mf)                                \
            af[mf] = *reinterpret_cast<const bf16x8*>(                                  \
                &As[(wr * 64 + mf * 16 + lr) * 32 + lh * 8]);                           \
        _Pragma("unroll") for (int nf = 0; nf < 4; ++nf)                                \
            bf[nf] = *reinterpret_cast<const bf16x8*>(                                  \
                &Bs[(wc * 64 + nf * 16 + lr) * 32 + lh * 8]);                           \
        _Pragma("unroll") for (int mf = 0; mf < 4; ++mf)                                \
            _Pragma("unroll") for (int nf = 0; nf < 4; ++nf)                            \
                acc[mf][nf] = mfma16(af[mf], bf[nf], acc[mf][nf]);                      \
        __syncthreads();                                                                \
    }

// ---- QKV GEMM ----
__global__ __launch_bounds__(256) void gemm_qkv_kernel(
    const __hip_bfloat16* __restrict__ A, const __hip_bfloat16* __restrict__ Bt,
    const float* __restrict__ bias,
    __hip_bfloat16* __restrict__ qd, __hip_bfloat16* __restrict__ kd,
    __hip_bfloat16* __restrict__ vtd) {
    const int K = 1024;
    const int m0 = blockIdx.x * 128;
    const int n0 = blockIdx.y * 128;
    GEMM128_BODY(A, Bt, K)

    const int region = n0 >> 10;  // 0:q 1:k 2:v (block-uniform)
#pragma unroll
    for (int mf = 0; mf < 4; ++mf) {
#pragma unroll
        for (int nf = 0; nf < 4; ++nf) {
            int n = n0 + wc * 64 + nf * 16 + lr;
            float bv = bias[n];
            int mbase = m0 + wr * 64 + mf * 16 + 4 * lh;
            int bb = mbase >> 11;
            int t = mbase & 2047;
            int c = n & 1023, hh = c >> 6, dd = c & 63;
            if (region == 2) {
                union { __hip_bfloat16 h[4]; uint2 v; } pk;
#pragma unroll
                for (int r = 0; r < 4; ++r) pk.h[r] = __float2bfloat16(acc[mf][nf][r] + bv);
                *reinterpret_cast<uint2*>(
                    &vtd[(((size_t)bb * 16 + hh) * 64 + dd) * 2048 + t]) = pk.v;
            } else if (region == 0) {
#pragma unroll
                for (int r = 0; r < 4; ++r)
                    qd[(((size_t)bb * 16 + hh) * 2048 + t + r) * 64 + dd] =
                        __float2bfloat16((acc[mf][nf][r] + bv) * QSCL);
            } else {
#pragma unroll
                for (int r = 0; r < 4; ++r)
                    kd[(((size_t)bb * 16 + hh) * 2048 + t + r) * 64 + dd] =
                        __float2bfloat16(acc[mf][nf][r] + bv);
            }
        }
    }
}

// ---- proj GEMM ----
__global__ __launch_bounds__(256) void gemm_proj_kernel(
    const __hip_bfloat16* __restrict__ A, const __hip_bfloat16* __restrict__ Bt,
    const float* __restrict__ bias, float* __restrict__ out) {
    const int K = 1024, N = 1024;
    const int m0 = blockIdx.x * 128;
    const int n0 = blockIdx.y * 128;
    GEMM128_BODY(A, Bt, K)

#pragma unroll
    for (int nf = 0; nf < 4; ++nf) {
        int n = n0 + wc * 64 + nf * 16 + lr;
        float bv = bias[n];
#pragma unroll
        for (int mf = 0; mf < 4; ++mf) {
            int mbase = m0 + wr * 64 + mf * 16 + 4 * lh;
#pragma unroll
            for (int r = 0; r < 4; ++r)
                out[(size_t)(mbase + r) * N + n] = acc[mf][nf][r] + bv;
        }
    }
}

// ---- causal flash attention v6 ----
// One 64-row q-tile per block (4 waves x 16 rows) for max TLP:
// LDS 25.6KB, ~84 VGPR -> ~6 blocks/CU resident.
// 2048 blocks, XCD-swizzled (8 whole heads per XCD -> K/V fits its L2);
// within a head, longest q-tile dispatched first (backfill smooths tail).
// Single-buffered K/V staging via global_load_lds; softmax in exp2 domain;
// per-lane partial row sums; defer-max THR=8.
__global__ __launch_bounds__(256) void attn_kernel(
    const __hip_bfloat16* __restrict__ q, const __hip_bfloat16* __restrict__ k,
    const __hip_bfloat16* __restrict__ vt, __hip_bfloat16* __restrict__ y) {
    const int T = 2048, D = 64, C = 1024;
    const float THR = 8.0f;

    // XCD swizzle: wid = (bid&7)*256 + bid/8 ; 256 consecutive wids = 8 heads
    int wid = ((int)blockIdx.x & 7) * 256 + ((int)blockIdx.x >> 3);
    int bh = wid >> 5;
    int qt = 31 - (wid & 31);  // longest first within each head
    int b = bh >> 4, h = bh & 15;
    int tid = threadIdx.x;
    int w = tid >> 6, l = tid & 63;
    int lr = l & 15, lh = l >> 4;

    __shared__ __hip_bfloat16 Ks[64 * 64];  // [kv][d], xor-swizzled rows
    __shared__ __hip_bfloat16 Vs[64 * 64];  // [d][kv], xor-swizzled rows
    __shared__ __hip_bfloat16 P[4][16][72];

    const __hip_bfloat16* kbh = k + (size_t)bh * T * D;
    const __hip_bfloat16* vbh = vt + (size_t)bh * D * T;
    const int q0 = qt * 64 + w * 16;

    bf16x8 qa[2];
#pragma unroll
    for (int dd = 0; dd < 2; ++dd)
        qa[dd] = *reinterpret_cast<const bf16x8*>(
            q + ((size_t)bh * T + q0 + lr) * D + 32 * dd + 8 * lh);

    f32x4 zero = {0.f, 0.f, 0.f, 0.f};
    f32x4 o[4] = {zero, zero, zero, zero};
    float m[4], lp[4];
#pragma unroll
    for (int r = 0; r < 4; ++r) { m[r] = -INFINITY; lp[r] = 0.f; }

    for (int t = 0; t <= qt; ++t) {
        int kv0 = t * 64;
        __syncthreads();  // prev iteration's LDS reads complete before overwrite
        // ---- stage K and V tiles (both-sides swizzle: pre-swizzled source) ----
#pragma unroll
        for (int j = 0; j < 2; ++j) {
            int slot = j * 256 + tid;
            int row = slot >> 3;
            int colb = ((slot & 7) * 16) ^ ((row & 7) << 4);
            async_copy16(kbh + (size_t)(kv0 + row) * 64 + (colb >> 1),
                         Ks + (size_t)(j * 256 + w * 64) * 8);
            async_copy16(vbh + (size_t)row * T + kv0 + (colb >> 1),
                         Vs + (size_t)(j * 256 + w * 64) * 8);
        }
        __syncthreads();  // drains vmcnt

        // K frags from LDS (swizzled)
        bf16x8 kb[4][2];
#pragma unroll
        for (int ct = 0; ct < 4; ++ct)
#pragma unroll
            for (int dd = 0; dd < 2; ++dd) {
                int row = 16 * ct + lr;
                int colb = (dd * 64 + lh * 16) ^ ((lr & 7) << 4);
                kb[ct][dd] = *reinterpret_cast<const bf16x8*>(
                    reinterpret_cast<const char*>(Ks) + row * 128 + colb);
            }

        f32x4 s[4];
#pragma unroll
        for (int ct = 0; ct < 4; ++ct) {
            f32x4 acc = zero;
            acc = mfma16(qa[0], kb[ct][0], acc);
            acc = mfma16(qa[1], kb[ct][1], acc);
            s[ct] = acc;
        }

        // V frags from LDS (swizzled) — issue early, latency hides under softmax
        bf16x8 vb[4][2];
#pragma unroll
        for (int dt = 0; dt < 4; ++dt)
#pragma unroll
            for (int kk = 0; kk < 2; ++kk) {
                int row = 16 * dt + lr;
                int colb = (kk * 64 + lh * 16) ^ ((lr & 7) << 4);
                vb[dt][kk] = *reinterpret_cast<const bf16x8*>(
                    reinterpret_cast<const char*>(Vs) + row * 128 + colb);
            }

        // mask (diagonal tile only)
        if (t == qt) {
#pragma unroll
            for (int ct = 0; ct < 4; ++ct)
#pragma unroll
                for (int r = 0; r < 4; ++r) {
                    int qq = q0 + 4 * lh + r;
                    int kc = kv0 + 16 * ct + lr;
                    if (kc > qq) s[ct][r] = -INFINITY;
                }
        }

        // row max of tile
        float mx[4];
#pragma unroll
        for (int r = 0; r < 4; ++r)
            mx[r] = fmaxf(fmaxf(s[0][r], s[1][r]), fmaxf(s[2][r], s[3][r]));
#pragma unroll
        for (int d = 1; d < 16; d <<= 1)
#pragma unroll
            for (int r = 0; r < 4; ++r) mx[r] = fmaxf(mx[r], __shfl_xor(mx[r], d, 16));

        // defer-max: rescale only when growth exceeds THR
        bool small = (mx[0] - m[0] <= THR) && (mx[1] - m[1] <= THR) &&
                     (mx[2] - m[2] <= THR) && (mx[3] - m[3] <= THR);
        if (!__all(small)) {
#pragma unroll
            for (int r = 0; r < 4; ++r) {
                float mnew = fmaxf(m[r], mx[r]);
                float al = __builtin_amdgcn_exp2f(m[r] - mnew);
                m[r] = mnew;
                lp[r] *= al;
#pragma unroll
                for (int dt = 0; dt < 4; ++dt) o[dt][r] *= al;
            }
        }

        // p = exp2(s - m); per-lane partial row sums
#pragma unroll
        for (int ct = 0; ct < 4; ++ct)
#pragma unroll
            for (int r = 0; r < 4; ++r)
                s[ct][r] = __builtin_amdgcn_exp2f(s[ct][r] - m[r]);
#pragma unroll
        for (int r = 0; r < 4; ++r)
            lp[r] += (s[0][r] + s[1][r]) + (s[2][r] + s[3][r]);

        // pack P (wave-internal LDS, no barrier)
#pragma unroll
        for (int ct = 0; ct < 4; ++ct)
#pragma unroll
            for (int r = 0; r < 4; ++r)
                P[w][4 * lh + r][16 * ct + lr] = __float2bfloat16(s[ct][r]);

        bf16x8 pa0 = *reinterpret_cast<const bf16x8*>(&P[w][lr][8 * lh]);
        bf16x8 pa1 = *reinterpret_cast<const bf16x8*>(&P[w][lr][32 + 8 * lh]);
#pragma unroll
        for (int dt = 0; dt < 4; ++dt) {
            o[dt] = mfma16(pa0, vb[dt][0], o[dt]);
            o[dt] = mfma16(pa1, vb[dt][1], o[dt]);
        }
    }

    // reduce row sums across the 16 lanes, once per q-tile
#pragma unroll
    for (int d = 1; d < 16; d <<= 1)
#pragma unroll
        for (int r = 0; r < 4; ++r) lp[r] += __shfl_xor(lp[r], d, 16);

    float inv[4];
#pragma unroll
    for (int r = 0; r < 4; ++r) inv[r] = 1.0f / lp[r];
#pragma unroll
    for (int dt = 0; dt < 4; ++dt)
#pragma unroll
        for (int r = 0; r < 4; ++r) {
            int qq = q0 + 4 * lh + r;
            y[((size_t)b * T + qq) * C + h * 64 + dt * 16 + lr] =
                __float2bfloat16(o[dt][r] * inv[r]);
        }
}

extern "C" void kernel_launch(void* const* d_in, const int* in_sizes, int n_in,
                              void* d_out, int out_size, void* d_ws, size_t ws_size,
                              hipStream_t stream) {
    const float* x      = (const float*)d_in[0];
    const float* W_attn = (const float*)d_in[1];
    const float* b_attn = (const float*)d_in[2];
    const float* W_proj = (const float*)d_in[3];
    const float* b_proj = (const float*)d_in[4];
    float* out = (float*)d_out;

    __hip_bfloat16* wsb = reinterpret_cast<__hip_bfloat16*>(d_ws);
    __hip_bfloat16* xb  = wsb;                              // 8192*1024
    __hip_bfloat16* WaT = xb + (size_t)8192 * 1024;         // 3072*1024
    __hip_bfloat16* WpT = WaT + (size_t)3072 * 1024;        // 1024*1024
    __hip_bfloat16* qd  = WpT + (size_t)1024 * 1024;        // 64*2048*64
    __hip_bfloat16* kd  = qd + (size_t)64 * 2048 * 64;
    __hip_bfloat16* vtd = kd + (size_t)64 * 2048 * 64;
    __hip_bfloat16* ya  = vtd + (size_t)64 * 2048 * 64;     // 8192*1024

    cast_x_kernel<<<4096, 256, 0, stream>>>(x, xb, 8192 * 1024);
    transpose_cast_kernel<<<dim3(96, 32), 256, 0, stream>>>(W_attn, WaT, 1024, 3072);
    transpose_cast_kernel<<<dim3(32, 32), 256, 0, stream>>>(W_proj, WpT, 1024, 1024);
    gemm_qkv_kernel<<<dim3(64, 24), 256, 0, stream>>>(xb, WaT, b_attn, qd, kd, vtd);
    attn_kernel<<<2048, 256, 0, stream>>>(qd, kd, vtd, ya);
    gemm_proj_kernel<<<dim3(64, 8), 256, 0, stream>>>(ya, WpT, b_proj, out);
}